// Round 2
// baseline (145951.343 us; speedup 1.0000x reference)
//
#include <hip/hip_runtime.h>

typedef unsigned int u32;
typedef unsigned long long u64;

// ---------------- dims ----------------
// B=16 T=1024 F=80 H=1024 4H=4096 P=512 E=256 Hd=512 4Hd=2048 J=512 V=54 W=4 ML=55

// ---------------- workspace layout (units of 4 bytes) ----------------
static constexpr size_t O_WENC  = 0;                       // [128][1104][8jt][4g]
static constexpr size_t SZ_WENC = 128ull*1104*32;          // 4,521,984
static constexpr size_t O_WPROJ = O_WENC + SZ_WENC;        // [16][1024][8][4]
static constexpr size_t SZ_WPROJ= 16ull*1024*32;
static constexpr size_t O_WE    = O_WPROJ + SZ_WPROJ;      // [16][512][8][4]
static constexpr size_t SZ_WE   = 16ull*512*32;
static constexpr size_t O_WD    = O_WE + SZ_WE;            // [8][512][16][4]
static constexpr size_t SZ_WD   = 8ull*512*64;
static constexpr size_t O_WO    = O_WD + SZ_WD;            // [512][56]
static constexpr size_t SZ_WO   = 512*56;
static constexpr size_t O_DWP   = O_WO + SZ_WO;            // [8][512][64][4]
static constexpr size_t SZ_DWP  = 8ull*512*256;
static constexpr size_t O_MEMB  = O_DWP + SZ_DWP;          // [54][2048]
static constexpr size_t SZ_MEMB = 54*2048;
static constexpr size_t O_UALL  = O_MEMB + SZ_MEMB;        // [16][1024][512]
static constexpr size_t SZ_UALL = 16ull*1024*512;
static constexpr size_t O_HBUF  = O_UALL + SZ_UALL;        // [2][1024k][16b]
static constexpr size_t SZ_HBUF = 2*1024*16;
static constexpr size_t O_PRING = O_HBUF + SZ_HBUF;        // [2][512p][16b]
static constexpr size_t SZ_PRING= 2*512*16;
static constexpr size_t O_HDEC  = O_PRING + SZ_PRING;      // [2][16][4][512]
static constexpr size_t SZ_HDEC = 2*16*4*512;
static constexpr size_t O_CDEC  = O_HDEC + SZ_HDEC;
static constexpr size_t SZ_CDEC = SZ_HDEC;
static constexpr size_t O_VBUF  = O_CDEC + SZ_CDEC;        // [16][4][512]
static constexpr size_t SZ_VBUF = 16*4*512;
static constexpr size_t O_CUM   = O_VBUF + SZ_VBUF;        // [2][16][4]
static constexpr size_t SZ_CUM  = 2*16*4;
static constexpr size_t O_SEQS  = O_CUM + SZ_CUM;          // int [2][16][4][56]
static constexpr size_t SZ_SEQS = 2*16*4*56;
static constexpr size_t O_LENS  = O_SEQS + SZ_SEQS;        // int [2][16][4]
static constexpr size_t SZ_LENS = 2*16*4;
static constexpr size_t O_BAR   = O_LENS + SZ_LENS;        // u32 [4]

// prep segment bounds
static constexpr size_t E0 = SZ_WENC;
static constexpr size_t E1 = E0 + SZ_WPROJ;
static constexpr size_t E2 = E1 + SZ_WE;
static constexpr size_t E3 = E2 + SZ_WD;
static constexpr size_t E4 = E3 + SZ_WO;
static constexpr size_t E5 = E4 + SZ_DWP;
static constexpr size_t E6 = E5 + SZ_MEMB;
static constexpr size_t E7 = E6 + 16384;    // h_buf parity-1 zeros
static constexpr size_t E8 = E7 + 32768;    // hdec ring0 zeros
static constexpr size_t E9 = E8 + 32768;    // cdec ring0 zeros
static constexpr size_t E10 = E9 + 64;      // cum ring0
static constexpr size_t E11 = E10 + 3584;   // seqs ring0 zeros (int)
static constexpr size_t E12 = E11 + 64;     // lens ring0 zeros (int)
static constexpr size_t ETOT = E12 + 4;     // barrier words

#define AL(p)    __hip_atomic_load((p), __ATOMIC_RELAXED, __HIP_MEMORY_SCOPE_AGENT)
#define AS(p,v)  __hip_atomic_store((p), (v), __ATOMIC_RELAXED, __HIP_MEMORY_SCOPE_AGENT)

// fp64 accumulation of fp32 data: keeps our partial sums ~exact so the only
// divergence vs the np reference is np's own rounding (minimizes top-k flips).
#define FMA16D(A, W, H) { \
  const double wx=(double)(W).x, wy=(double)(W).y, wz=(double)(W).z, ww=(double)(W).w; \
  const double hx=(double)(H).x, hy=(double)(H).y, hz=(double)(H).z, hw=(double)(H).w; \
  A[0]+=wx*hx; A[1]+=wx*hy; A[2]+=wx*hz; A[3]+=wx*hw; \
  A[4]+=wy*hx; A[5]+=wy*hy; A[6]+=wy*hz; A[7]+=wy*hw; \
  A[8]+=wz*hx; A[9]+=wz*hy; A[10]+=wz*hz; A[11]+=wz*hw; \
  A[12]+=ww*hx; A[13]+=ww*hy; A[14]+=ww*hz; A[15]+=ww*hw; }

// np-matching f32 activation chains (double-evaluated transcendentals, unfused f32 ops)
__device__ __forceinline__ float sig_np(float x) {
  const float ex = (float)exp(-(double)x);
  return __fdiv_rn(1.0f, __fadd_rn(1.0f, ex));
}
__device__ __forceinline__ float tanh_np(float x) { return (float)tanh((double)x); }

// grid barrier with a full acq/rel chain:
//  arrive: ACQ_REL fetch_add on cnt (release own data; last arriver acquires all)
//  publish: RELEASE fetch_add on gen
//  spin: relaxed, then one ACQUIRE load of gen (invalidates caches -> fresh data)
__device__ __forceinline__ void gbar(u32* cnt, u32* gen, u32 nb) {
  __syncthreads();
  if (threadIdx.x == 0) {
    u32 g = __hip_atomic_load(gen, __ATOMIC_RELAXED, __HIP_MEMORY_SCOPE_AGENT);
    u32 old = __hip_atomic_fetch_add(cnt, 1u, __ATOMIC_ACQ_REL, __HIP_MEMORY_SCOPE_AGENT);
    if (old == nb - 1u) {
      __hip_atomic_store(cnt, 0u, __ATOMIC_RELAXED, __HIP_MEMORY_SCOPE_AGENT);
      __hip_atomic_fetch_add(gen, 1u, __ATOMIC_RELEASE, __HIP_MEMORY_SCOPE_AGENT);
    } else {
      while (__hip_atomic_load(gen, __ATOMIC_RELAXED, __HIP_MEMORY_SCOPE_AGENT) == g)
        __builtin_amdgcn_s_sleep(2);
      (void)__hip_atomic_load(gen, __ATOMIC_ACQUIRE, __HIP_MEMORY_SCOPE_AGENT);
    }
  }
  __syncthreads();
}

__device__ __forceinline__ u32 orderb(float f) {
  u32 u = __float_as_uint(f);
  return (u & 0x80000000u) ? ~u : (u | 0x80000000u);
}
__device__ __forceinline__ float unorderb(u32 u) {
  return __uint_as_float((u & 0x80000000u) ? (u & 0x7fffffffu) : ~u);
}
__device__ __forceinline__ u64 sx64(u64 v, int m) {
  u32 lo = __shfl_xor((u32)v, m, 64);
  u32 hi = __shfl_xor((u32)(v >> 32), m, 64);
  return (((u64)hi) << 32) | lo;
}
__device__ __forceinline__ double sxd(double v, int m) {
  u64 b = (u64)__double_as_longlong(v);
  u32 lo = __shfl_xor((u32)b, m, 64);
  u32 hi = __shfl_xor((u32)(b >> 32), m, 64);
  return __longlong_as_double((long long)((((u64)hi) << 32) | lo));
}

// ================= prep: weight packing + state init =================
__global__ void k_prep(const float* __restrict__ eWih, const float* __restrict__ eWhh,
                       const float* __restrict__ pW,   const float* __restrict__ emb,
                       const float* __restrict__ dWih, const float* __restrict__ dWhh,
                       const float* __restrict__ dbb,  const float* __restrict__ We,
                       const float* __restrict__ Wd,   const float* __restrict__ Wo,
                       float* __restrict__ ws)
{
  const size_t stride = (size_t)gridDim.x * blockDim.x;
  int* wsi = (int*)ws;
  for (size_t e = (size_t)blockIdx.x * blockDim.x + threadIdx.x; e < ETOT; e += stride) {
    if (e < E0) {                          // Wenc [kb][kk1104][jt8][g4]
      size_t kb = e / 35328, r = e % 35328;
      size_t kk = r >> 5, r2 = r & 31, jt = r2 >> 2, g = r2 & 3;
      size_t row = g * 1024 + kb * 8 + jt;
      ws[O_WENC + e] = (kk < 1024) ? eWhh[row * 1024 + kk] : eWih[row * 80 + (kk - 1024)];
    } else if (e < E1) { size_t t = e - E0; // Wproj [pb][kk1024][jt8][c4]
      size_t pb = t / 32768, r = t % 32768;
      size_t kk = r >> 5, r2 = r & 31, jt = r2 >> 2, c = r2 & 3;
      ws[O_WPROJ + t] = pW[(pb * 32 + jt * 4 + c) * 1024 + kk];
    } else if (e < E2) { size_t t = e - E1; // WeP [ub][kk512][jt8][c4]
      size_t ub = t / 16384, r = t % 16384;
      size_t kk = r >> 5, r2 = r & 31, jt = r2 >> 2, c = r2 & 3;
      ws[O_WE + t] = We[(ub * 32 + jt * 4 + c) * 512 + kk];
    } else if (e < E3) { size_t t = e - E2; // WdP [js][kk512][jt16][c4]
      size_t js = t / 32768, r = t % 32768;
      size_t kk = r >> 6, r2 = r & 63, jt = r2 >> 2, c = r2 & 3;
      ws[O_WD + t] = Wd[(js * 64 + jt * 4 + c) * 512 + kk];
    } else if (e < E4) { size_t t = e - E3; // WoT [kk512][56]
      size_t kk = t / 56, vv = t % 56;
      ws[O_WO + t] = (vv < 54) ? Wo[vv * 512 + kk] : 0.f;
    } else if (e < E5) { size_t t = e - E4; // dWP [ks][kk512][kl64][g4]
      size_t ks = t / 131072, r = t % 131072;
      size_t kk = r >> 8, r2 = r & 255, kl = r2 >> 2, g = r2 & 3;
      ws[O_DWP + t] = dWhh[(g * 512 + ks * 64 + kl) * 512 + kk];
    } else if (e < E6) { size_t t = e - E5; // Memb [tok][2048] = dWih@emb (+db=0)
      size_t tok = t / 2048, j = t % 2048;
      double s = 0.0;
      const float* wr = dWih + j * 256;
      const float* er = emb + tok * 256;
      for (int q = 0; q < 256; ++q) s += (double)wr[q] * (double)er[q];
      ws[O_MEMB + t] = (float)(s + (double)dbb[j]);
    } else if (e < E7)  { ws[O_HBUF + 16384 + (e - E6)] = 0.f; }
    else if (e < E8)  { ws[O_HDEC + (e - E7)] = 0.f; }
    else if (e < E9)  { ws[O_CDEC + (e - E8)] = 0.f; }
    else if (e < E10) { size_t t = e - E9; ws[O_CUM + t] = ((t & 3) == 0) ? 0.f : -1000000000.0f; }
    else if (e < E11) { wsi[O_SEQS + (e - E10)] = 0; }
    else if (e < E12) { wsi[O_LENS + (e - E11)] = 0; }
    else              { wsi[O_BAR + (e - E12)] = 0; }
  }
}

// ================= encoder + projection + joint-We precompute =================
// 160 blocks: [0,128) encoder (8 units x 4 gates x 16 batches, c in regs),
// [128,144) projection (1 step behind), [144,160) u = We@p + bj (2 behind).
__global__ __launch_bounds__(256, 1) void k_enc(
    const float* __restrict__ xin, const float* __restrict__ encb,
    const float* __restrict__ projb, const float* __restrict__ bjv,
    float* __restrict__ ws)
{
  __shared__ float  s_hx[8832];   // [<=552 rows][16 b]
  __shared__ double s_redd[4096]; // r-major [16][256]
  const int tid = threadIdx.x, blk = blockIdx.x;
  const int kc = tid >> 5, bt = (tid >> 3) & 3, jt = tid & 7;
  u32* bar = (u32*)ws + O_BAR;
  float* hb = ws + O_HBUF;
  float* prn = ws + O_PRING;
  float* ua = ws + O_UALL;

  float creg[4] = {0.f, 0.f, 0.f, 0.f};
  float bb0 = 0.f, bb1 = 0.f, bb2 = 0.f, bb3 = 0.f;
  if (tid < 32) {
    if (blk < 128) {
      const int k = blk * 8 + (tid & 7);
      bb0 = encb[k]; bb1 = encb[1024 + k]; bb2 = encb[2048 + k]; bb3 = encb[3072 + k];
    } else if (blk < 144) {
      const int pj = (blk - 128) * 32 + (tid & 7) * 4;
      bb0 = projb[pj]; bb1 = projb[pj + 1]; bb2 = projb[pj + 2]; bb3 = projb[pj + 3];
    } else {
      const int uj = (blk - 144) * 32 + (tid & 7) * 4;
      bb0 = bjv[uj]; bb1 = bjv[uj + 1]; bb2 = bjv[uj + 2]; bb3 = bjv[uj + 3];
    }
  }

  for (int i = 0; i < 1026; ++i) {
    if (blk < 128 && i < 1024) {
      // ---- encoder LSTM step t=i: z = (x@Wih.T)_f32 + (h@Whh.T)_f32 + b ----
      const int par = (i + 1) & 1;
      double ah[16], ax[16];
      #pragma unroll
      for (int r = 0; r < 16; ++r) { ah[r] = 0.0; ax[r] = 0.0; }
      const float4* wb = (const float4*)(ws + O_WENC) + ((size_t)blk * 8832 + (size_t)kc * 552 + jt);
      // pass 0: kk 0..551 (all h)
      for (int e = tid; e < 8832; e += 256) s_hx[e] = AL(hb + par * 16384 + e);
      __syncthreads();
      {
        const float* hxp = s_hx + kc * 1104 + bt * 4;
        for (int q = 0; q < 69; ++q) {
          const float4 w4 = wb[(size_t)q * 8];
          const float4 h4 = *(const float4*)(hxp + q * 16);
          FMA16D(ah, w4, h4);
        }
      }
      __syncthreads();
      // pass 1: kk 552..1103 (h below 1024, x above)
      for (int e = tid; e < 8832; e += 256) {
        float v;
        if (e < 7552) v = AL(hb + par * 16384 + 8832 + e);
        else { const int f = (e - 7552) >> 4, bq = e & 15;
               v = xin[((size_t)bq * 1024 + i) * 80 + f]; }
        s_hx[e] = v;
      }
      __syncthreads();
      {
        const float4* wp = wb + 4416;
        const float* hxp = s_hx + kc * 1104 + bt * 4;
        int qs = 472 - kc * 69; qs = qs < 0 ? 0 : (qs > 69 ? 69 : qs);
        for (int q = 0; q < qs; ++q) {
          const float4 w4 = wp[(size_t)q * 8];
          const float4 h4 = *(const float4*)(hxp + q * 16);
          FMA16D(ah, w4, h4);
        }
        for (int q = qs; q < 69; ++q) {
          const float4 w4 = wp[(size_t)q * 8];
          const float4 h4 = *(const float4*)(hxp + q * 16);
          FMA16D(ax, w4, h4);
        }
      }
      __syncthreads();
      #pragma unroll
      for (int r = 0; r < 16; ++r) s_redd[r * 256 + tid] = ah[r];
      __syncthreads();
      double Sh[16];
      if (tid < 32) {
        #pragma unroll
        for (int r = 0; r < 16; ++r) {
          double s0 = 0.0;
          #pragma unroll
          for (int k8 = 0; k8 < 8; ++k8) s0 += s_redd[r * 256 + k8 * 32 + tid];
          Sh[r] = s0;
        }
      }
      __syncthreads();
      #pragma unroll
      for (int r = 0; r < 16; ++r) s_redd[r * 256 + tid] = ax[r];
      __syncthreads();
      if (tid < 32) {
        float zf32[16];
        #pragma unroll
        for (int r = 0; r < 16; ++r) {
          double s0 = 0.0;
          #pragma unroll
          for (int k8 = 0; k8 < 8; ++k8) s0 += s_redd[r * 256 + k8 * 32 + tid];
          const float bbg = (r < 4) ? bb0 : (r < 8) ? bb1 : (r < 12) ? bb2 : bb3;
          zf32[r] = __fadd_rn(__fadd_rn((float)s0, (float)Sh[r]), bbg);
        }
        const int k = blk * 8 + (tid & 7);
        const int bt0 = tid >> 3;
        float* hout = hb + (i & 1) * 16384 + k * 16 + bt0 * 4;
        #pragma unroll
        for (int q = 0; q < 4; ++q) {
          const float zi = zf32[q], zf = zf32[4 + q], zg = zf32[8 + q], zo = zf32[12 + q];
          const float cn = __fadd_rn(__fmul_rn(sig_np(zf), creg[q]),
                                     __fmul_rn(sig_np(zi), tanh_np(zg)));
          const float hn = __fmul_rn(sig_np(zo), tanh_np(cn));
          creg[q] = cn;
          AS(hout + q, hn);
        }
      }
    } else if (blk >= 128 && blk < 144 && i >= 1 && i <= 1024) {
      // ---- projection of h_{i-1}: h@proj_W.T + proj_b ----
      const int pb = blk - 128, par = (i + 1) & 1;
      double ah[16];
      #pragma unroll
      for (int r = 0; r < 16; ++r) ah[r] = 0.0;
      const float4* wb = (const float4*)(ws + O_WPROJ) + ((size_t)pb * 8192 + (size_t)kc * 512 + jt);
      for (int pass = 0; pass < 2; ++pass) {
        for (int e = tid; e < 8192; e += 256)
          s_hx[e] = AL(hb + par * 16384 + pass * 8192 + e);
        __syncthreads();
        const float4* wp = wb + (size_t)pass * 4096;
        const float* hxp = s_hx + kc * 1024 + bt * 4;
        for (int q = 0; q < 64; ++q) {
          const float4 w4 = wp[(size_t)q * 8];
          const float4 h4 = *(const float4*)(hxp + q * 16);
          FMA16D(ah, w4, h4);
        }
        __syncthreads();
      }
      #pragma unroll
      for (int r = 0; r < 16; ++r) s_redd[r * 256 + tid] = ah[r];
      __syncthreads();
      if (tid < 32) {
        const int pj = pb * 32 + (tid & 7) * 4;
        const int bt0 = tid >> 3;
        #pragma unroll
        for (int r = 0; r < 16; ++r) {
          double s0 = 0.0;
          #pragma unroll
          for (int k8 = 0; k8 < 8; ++k8) s0 += s_redd[r * 256 + k8 * 32 + tid];
          const int c = r >> 2, bq = r & 3;
          const float bias = (c == 0 ? bb0 : c == 1 ? bb1 : c == 2 ? bb2 : bb3);
          AS(prn + (i & 1) * 8192 + (pj + c) * 16 + bt0 * 4 + bq, __fadd_rn((float)s0, bias));
        }
      }
    } else if (blk >= 144 && i >= 2) {
      // ---- u = p_{i-2}@We.T + bj ----
      const int ub = blk - 144, par = (i + 1) & 1, sv = i - 2;
      double ah[16];
      #pragma unroll
      for (int r = 0; r < 16; ++r) ah[r] = 0.0;
      const float4* wb = (const float4*)(ws + O_WE) + ((size_t)ub * 4096 + (size_t)kc * 512 + jt);
      for (int e = tid; e < 8192; e += 256) s_hx[e] = AL(prn + par * 8192 + e);
      __syncthreads();
      {
        const float* hxp = s_hx + kc * 1024 + bt * 4;
        for (int q = 0; q < 64; ++q) {
          const float4 w4 = wb[(size_t)q * 8];
          const float4 h4 = *(const float4*)(hxp + q * 16);
          FMA16D(ah, w4, h4);
        }
      }
      #pragma unroll
      for (int r = 0; r < 16; ++r) s_redd[r * 256 + tid] = ah[r];
      __syncthreads();
      if (tid < 32) {
        const int uj = ub * 32 + (tid & 7) * 4;
        const int bt0 = tid >> 3;
        #pragma unroll
        for (int r = 0; r < 16; ++r) {
          double s0 = 0.0;
          #pragma unroll
          for (int k8 = 0; k8 < 8; ++k8) s0 += s_redd[r * 256 + k8 * 32 + tid];
          const int c = r >> 2, bq = r & 3;
          const float bias = (c == 0 ? bb0 : c == 1 ? bb1 : c == 2 ? bb2 : bb3);
          ua[((size_t)(bt0 * 4 + bq) * 1024 + sv) * 512 + uj + c] = __fadd_rn((float)s0, bias);
        }
      }
    }
    gbar(bar, bar + 1, 160u);
  }
}

// ================= beam-search decoder =================
// 16 blocks/batch. Phase A: roles 0..7 compute v = tanh(u + Wd h). Phase B:
// ALL 16 blocks redundantly compute logits/softmax/top-k (bit-identical), then
// each block updates the LSTM state for its own 32 units. 2 barriers/step.
__global__ __launch_bounds__(256, 1) void k_dec(
    const int* __restrict__ linp, const float* __restrict__ bo,
    int* __restrict__ outp, float* __restrict__ ws)
{
  __shared__ float  s_h[2048], s_v[2048], s_c[128];
  __shared__ double s_redd[4096];
  __shared__ float  s_cand[216];
  __shared__ int s_parent[4], s_tok[4], s_plen[4], s_emit[4];
  __shared__ float s_val[4];
  const int tid = threadIdx.x, blk = blockIdx.x;
  const int b = blk >> 4, role = blk & 15;
  const int L = linp[b];
  u32* bar = (u32*)ws + O_BAR + 2;
  float* hd = ws + O_HDEC;
  float* cd = ws + O_CDEC;
  float* vb = ws + O_VBUF;
  float* cum = ws + O_CUM;
  int* seqs = (int*)ws + O_SEQS;
  int* lensr = (int*)ws + O_LENS;

  for (int s = 0; s < 1024; ++s) {
    const int cur = s & 1, nxt = cur ^ 1;
    const bool act = (s < L);
    if (act) {
      for (int e = tid; e < 2048; e += 256) s_h[e] = AL(hd + cur * 32768 + b * 2048 + e);
      if (tid < 128)
        s_c[tid] = AL(cd + cur * 32768 + b * 2048 + (tid >> 5) * 512 + role * 32 + (tid & 31));
      __syncthreads();
      if (role < 8) {
        // phase A: v-slice js=role: t = u + (h@Wd.T); v = tanh(t)
        const int js = role, kcA = tid >> 4, jt4 = tid & 15;
        double a[16];
        #pragma unroll
        for (int r = 0; r < 16; ++r) a[r] = 0.0;
        const float4* wp = (const float4*)(ws + O_WD) + ((size_t)js * 8192 + (size_t)kcA * 512 + jt4);
        for (int q = 0; q < 32; ++q) {
          const float4 w4 = wp[(size_t)q * 16];
          const int kk = kcA * 32 + q;
          const double wx = w4.x, wy = w4.y, wz = w4.z, ww = w4.w;
          #pragma unroll
          for (int w = 0; w < 4; ++w) {
            const double hv = (double)s_h[w * 512 + kk];
            a[w * 4 + 0] += wx * hv; a[w * 4 + 1] += wy * hv;
            a[w * 4 + 2] += wz * hv; a[w * 4 + 3] += ww * hv;
          }
        }
        #pragma unroll
        for (int r = 0; r < 16; ++r) s_redd[r * 256 + tid] = a[r];
        __syncthreads();
        if (tid < 16) {
          const float* up = ws + O_UALL + ((size_t)b * 1024 + s) * 512 + js * 64 + tid * 4;
          #pragma unroll
          for (int r = 0; r < 16; ++r) {
            double S = 0.0;
            #pragma unroll
            for (int k16 = 0; k16 < 16; ++k16) S += s_redd[r * 256 + k16 * 16 + tid];
            const int w = r >> 2, c = r & 3;
            const float t = __fadd_rn(up[c], (float)S);
            AS(vb + b * 2048 + w * 512 + js * 64 + tid * 4 + c, tanh_np(t));
          }
        }
      }
    }
    gbar(bar, bar + 1, 256u);
    if (act) {
      for (int e = tid; e < 2048; e += 256) s_v[e] = AL(vb + b * 2048 + e);
      __syncthreads();
      if (tid < 216) {            // logits = v@Wo.T + bo
        const int w = tid / 54, vv = tid - w * 54;
        const float* wo = ws + O_WO + vv;
        const float* vr = s_v + w * 512;
        double acc = 0.0;
        for (int kk = 0; kk < 512; ++kk) acc += (double)vr[kk] * (double)wo[(size_t)kk * 56];
        s_cand[tid] = __fadd_rn((float)acc, bo[vv]);
      }
      __syncthreads();
      {                           // log_softmax + cum -> candidates
        const int w = tid >> 6, lane = tid & 63;
        const float val = (lane < 54) ? s_cand[w * 54 + lane] : -3.0e38f;
        float m = val;
        #pragma unroll
        for (int off = 32; off > 0; off >>= 1) m = fmaxf(m, __shfl_xor(m, off, 64));
        const float sh = __fsub_rn(val, m);
        const float exf = (lane < 54) ? (float)exp((double)sh) : 0.f;
        double sum = (double)exf;
        #pragma unroll
        for (int off = 32; off > 0; off >>= 1) sum += sxd(sum, off);
        const float Sf = (float)sum;
        const float lg = (float)log((double)Sf);
        const float cw = AL(cum + cur * 64 + b * 4 + w);
        if (lane < 54) s_cand[w * 54 + lane] = __fadd_rn(cw, __fsub_rn(sh, lg));
      }
      __syncthreads();
      if (tid < 64) {             // top-4 of 216, lax.top_k tie-break (lower idx)
        u64 k4[4];
        #pragma unroll
        for (int p = 0; p < 4; ++p) {
          const int idx = tid + p * 64;
          k4[p] = (idx < 216) ? ((((u64)orderb(s_cand[idx])) << 32) | (u32)(~(u32)idx)) : 0ull;
        }
        #pragma unroll
        for (int sel = 0; sel < 4; ++sel) {
          u64 best = k4[0];
          if (k4[1] > best) best = k4[1];
          if (k4[2] > best) best = k4[2];
          if (k4[3] > best) best = k4[3];
          #pragma unroll
          for (int off = 32; off > 0; off >>= 1) { u64 o = sx64(best, off); if (o > best) best = o; }
          const u32 wid = ~((u32)best);
          if (tid == 0) {
            s_parent[sel] = (int)(wid / 54u);
            s_tok[sel] = (int)(wid - (wid / 54u) * 54u);
            s_val[sel] = unorderb((u32)(best >> 32));
          }
          #pragma unroll
          for (int p = 0; p < 4; ++p) if ((u32)(tid + p * 64) == wid) k4[p] = 0ull;
        }
        if (tid == 0) {
          #pragma unroll
          for (int w = 0; w < 4; ++w) {
            const int pl = AL(lensr + cur * 64 + b * 4 + s_parent[w]);
            s_plen[w] = pl;
            s_emit[w] = (s_tok[w] != 0 && pl < 54) ? 1 : 0;
          }
        }
      }
      __syncthreads();
      if (role == 0) {            // single writer of seqs/lens/cum rings
        if (tid < 4) {
          AS(cum + nxt * 64 + b * 4 + tid, s_val[tid]);
          AS(lensr + nxt * 64 + b * 4 + tid, s_plen[tid] + s_emit[tid]);
        }
        for (int e = tid; e < 220; e += 256) {
          const int w = e / 55, m = e - w * 55;
          int v = AL(seqs + cur * 3584 + (b * 4 + s_parent[w]) * 56 + m);
          if (s_emit[w] && m == s_plen[w]) v = s_tok[w];
          AS(seqs + nxt * 3584 + (b * 4 + w) * 56 + m, v);
        }
      }
      {                           // decoder LSTM gates for this block's 32 units
        const int kc2 = tid >> 5, ul = tid & 31;
        const int ksb = role >> 1, klb = (role & 1) * 32 + ul;
        double a[16];
        #pragma unroll
        for (int r = 0; r < 16; ++r) a[r] = 0.0;
        const float4* wp = (const float4*)(ws + O_DWP) + (size_t)ksb * 32768 + (size_t)kc2 * 4096 + klb;
        const int p0 = s_parent[0] * 512, p1 = s_parent[1] * 512,
                  p2 = s_parent[2] * 512, p3 = s_parent[3] * 512;
        for (int q = 0; q < 64; ++q) {
          const float4 w4 = wp[(size_t)q * 64];
          const int kk = kc2 * 64 + q;
          const double wx = w4.x, wy = w4.y, wz = w4.z, ww = w4.w;
          const double h0 = s_h[p0 + kk], h1 = s_h[p1 + kk],
                       h2 = s_h[p2 + kk], h3 = s_h[p3 + kk];
          a[0] += wx * h0;  a[1] += wy * h0;  a[2] += wz * h0;  a[3] += ww * h0;
          a[4] += wx * h1;  a[5] += wy * h1;  a[6] += wz * h1;  a[7] += ww * h1;
          a[8] += wx * h2;  a[9] += wy * h2;  a[10] += wz * h2; a[11] += ww * h2;
          a[12] += wx * h3; a[13] += wy * h3; a[14] += wz * h3; a[15] += ww * h3;
        }
        #pragma unroll
        for (int r = 0; r < 16; ++r) s_redd[r * 256 + tid] = a[r];
        __syncthreads();
        if (tid < 32) {
          const int k = role * 32 + tid;
          #pragma unroll
          for (int w = 0; w < 4; ++w) {
            double z0 = 0.0, z1 = 0.0, z2 = 0.0, z3 = 0.0;
            #pragma unroll
            for (int kcq = 0; kcq < 8; ++kcq) {
              const int base = kcq * 32 + tid;
              z0 += s_redd[(w * 4 + 0) * 256 + base];
              z1 += s_redd[(w * 4 + 1) * 256 + base];
              z2 += s_redd[(w * 4 + 2) * 256 + base];
              z3 += s_redd[(w * 4 + 3) * 256 + base];
            }
            const float* mb = ws + O_MEMB + (size_t)s_tok[w] * 2048;
            const float zi = __fadd_rn(mb[k], (float)z0);
            const float zf = __fadd_rn(mb[512 + k], (float)z1);
            const float zg = __fadd_rn(mb[1024 + k], (float)z2);
            const float zo = __fadd_rn(mb[1536 + k], (float)z3);
            const float cold = s_c[s_parent[w] * 32 + tid];
            float cn = __fadd_rn(__fmul_rn(sig_np(zf), cold),
                                 __fmul_rn(sig_np(zi), tanh_np(zg)));
            float hn = __fmul_rn(sig_np(zo), tanh_np(cn));
            if (!s_emit[w]) { hn = s_h[s_parent[w] * 512 + k]; cn = cold; }
            AS(hd + nxt * 32768 + b * 2048 + w * 512 + k, hn);
            AS(cd + nxt * 32768 + b * 2048 + w * 512 + k, cn);
          }
        }
      }
    }
    gbar(bar, bar + 1, 256u);
  }
  if (role == 0) {                // emit outputs: total (64x55) then best (16x55)
    const int fc = L & 1;
    for (int e = tid; e < 220; e += 256) {
      const int w = e / 55, m = e - w * 55;
      const int ln = AL(lensr + fc * 64 + b * 4 + w);
      int v = AL(seqs + fc * 3584 + (b * 4 + w) * 56 + m);
      if (m == ln) v = 53;
      outp[(b * 4 + w) * 55 + m] = v;
      if (w == 0) outp[3520 + b * 55 + m] = v;
    }
  }
}

extern "C" void kernel_launch(void* const* d_in, const int* in_sizes, int n_in,
                              void* d_out, int out_size, void* d_ws, size_t ws_size,
                              hipStream_t stream) {
  (void)in_sizes; (void)n_in; (void)out_size; (void)ws_size;
  const float* xin  = (const float*)d_in[0];
  const int*   lin  = (const int*)d_in[1];
  const float* eWih = (const float*)d_in[3];
  const float* eWhh = (const float*)d_in[4];
  const float* eb   = (const float*)d_in[5];
  const float* pW   = (const float*)d_in[6];
  const float* pb   = (const float*)d_in[7];
  const float* emb  = (const float*)d_in[8];
  const float* dWih = (const float*)d_in[9];
  const float* dWhh = (const float*)d_in[10];
  const float* db   = (const float*)d_in[11];
  const float* We   = (const float*)d_in[12];
  const float* Wd   = (const float*)d_in[13];
  const float* bj   = (const float*)d_in[14];
  const float* Wo   = (const float*)d_in[15];
  const float* bo   = (const float*)d_in[16];
  float* ws = (float*)d_ws;
  int* outp = (int*)d_out;

  hipLaunchKernelGGL(k_prep, dim3(8192), dim3(256), 0, stream,
                     eWih, eWhh, pW, emb, dWih, dWhh, db, We, Wd, Wo, ws);
  hipLaunchKernelGGL(k_enc, dim3(160), dim3(256), 0, stream, xin, eb, pb, bj, ws);
  hipLaunchKernelGGL(k_dec, dim3(256), dim3(256), 0, stream, lin, bo, outp, ws);
}

// Round 4
// 86965.460 us; speedup vs baseline: 1.6783x; 1.6783x over previous
//
#include <hip/hip_runtime.h>

typedef unsigned int u32;
typedef unsigned long long u64;

// ---------------- dims ----------------
// B=16 T=1024 F=80 H=1024 4H=4096 P=512 E=256 Hd=512 4Hd=2048 J=512 V=54 W=4 ML=55

// ---------------- workspace layout (units of 4 bytes) ----------------
static constexpr size_t O_WENC  = 0;                       // [128][1104][8jt][4g]
static constexpr size_t SZ_WENC = 128ull*1104*32;
static constexpr size_t O_WPROJ = O_WENC + SZ_WENC;        // [16][1024][8][4]
static constexpr size_t SZ_WPROJ= 16ull*1024*32;
static constexpr size_t O_WE    = O_WPROJ + SZ_WPROJ;      // [16][512][8][4]
static constexpr size_t SZ_WE   = 16ull*512*32;
static constexpr size_t O_WD    = O_WE + SZ_WE;            // [8][512][16][4]
static constexpr size_t SZ_WD   = 8ull*512*64;
static constexpr size_t O_WO    = O_WD + SZ_WD;            // [512][56]
static constexpr size_t SZ_WO   = 512*56;
static constexpr size_t O_DWP   = O_WO + SZ_WO;            // [8][512][64][4]
static constexpr size_t SZ_DWP  = 8ull*512*256;
static constexpr size_t O_MEMB  = O_DWP + SZ_DWP;          // [54][2048]
static constexpr size_t SZ_MEMB = 54*2048;
static constexpr size_t O_UALL  = O_MEMB + SZ_MEMB;        // [16][1024][512]
static constexpr size_t SZ_UALL = 16ull*1024*512;
static constexpr size_t O_HBUF  = O_UALL + SZ_UALL;        // [2][1024k][16b]
static constexpr size_t SZ_HBUF = 2*1024*16;
static constexpr size_t O_PRING = O_HBUF + SZ_HBUF;        // [2][512p][16b]
static constexpr size_t SZ_PRING= 2*512*16;
static constexpr size_t O_HDEC  = O_PRING + SZ_PRING;      // [2][16][4][512]
static constexpr size_t SZ_HDEC = 2*16*4*512;
static constexpr size_t O_CDEC  = O_HDEC + SZ_HDEC;
static constexpr size_t SZ_CDEC = SZ_HDEC;
static constexpr size_t O_VBUF  = O_CDEC + SZ_CDEC;        // [16][4][512]
static constexpr size_t SZ_VBUF = 16*4*512;
static constexpr size_t O_CUM   = O_VBUF + SZ_VBUF;        // [2][16][4]
static constexpr size_t SZ_CUM  = 2*16*4;
static constexpr size_t O_SEQS  = O_CUM + SZ_CUM;          // int [2][16][4][56]
static constexpr size_t SZ_SEQS = 2*16*4*56;
static constexpr size_t O_LENS  = O_SEQS + SZ_SEQS;        // int [2][16][4]
static constexpr size_t SZ_LENS = 2*16*4;
// barriers (u32): enc root @ +0 (cnt,gen); enc group g @ +32*(1+g), g<20;
// dec batch b @ +32*(21+b), b<16. Each pair on its own 128B line.
static constexpr size_t O_BAR   = O_LENS + SZ_LENS;
static constexpr size_t SZ_BAR  = 32*37;                   // 1184 u32

// prep segment bounds
static constexpr size_t E0 = SZ_WENC;
static constexpr size_t E1 = E0 + SZ_WPROJ;
static constexpr size_t E2 = E1 + SZ_WE;
static constexpr size_t E3 = E2 + SZ_WD;
static constexpr size_t E4 = E3 + SZ_WO;
static constexpr size_t E5 = E4 + SZ_DWP;
static constexpr size_t E6 = E5 + SZ_MEMB;
static constexpr size_t E7 = E6 + 16384;    // h_buf parity-1 zeros
static constexpr size_t E8 = E7 + 32768;    // hdec ring0 zeros
static constexpr size_t E9 = E8 + 32768;    // cdec ring0 zeros
static constexpr size_t E10 = E9 + 64;      // cum ring0
static constexpr size_t E11 = E10 + 3584;   // seqs ring0 zeros (int)
static constexpr size_t E12 = E11 + 64;     // lens ring0 zeros (int)
static constexpr size_t ETOT = E12 + SZ_BAR;

#define AL(p)    __hip_atomic_load((p), __ATOMIC_RELAXED, __HIP_MEMORY_SCOPE_AGENT)
#define AS(p,v)  __hip_atomic_store((p), (v), __ATOMIC_RELAXED, __HIP_MEMORY_SCOPE_AGENT)

// fp64 accumulation of fp32 data: partial sums ~exact, so divergence vs the
// np reference is only np's own rounding (minimizes top-k decision flips).
#define FMA16D(A, W, H) { \
  const double wx=(double)(W).x, wy=(double)(W).y, wz=(double)(W).z, ww=(double)(W).w; \
  const double hx=(double)(H).x, hy=(double)(H).y, hz=(double)(H).z, hw=(double)(H).w; \
  A[0]+=wx*hx; A[1]+=wx*hy; A[2]+=wx*hz; A[3]+=wx*hw; \
  A[4]+=wy*hx; A[5]+=wy*hy; A[6]+=wy*hz; A[7]+=wy*hw; \
  A[8]+=wz*hx; A[9]+=wz*hy; A[10]+=wz*hz; A[11]+=wz*hw; \
  A[12]+=ww*hx; A[13]+=ww*hy; A[14]+=ww*hz; A[15]+=ww*hw; }

__device__ __forceinline__ float sig_np(float x) {
  const float ex = (float)exp(-(double)x);
  return __fdiv_rn(1.0f, __fadd_rn(1.0f, ex));
}
__device__ __forceinline__ float tanh_np(float x) { return (float)tanh((double)x); }

// All cross-block data moves via AL/AS (sc0sc1 -> coherent at L3). Arrivals are
// RELEASE (drain vmcnt -> data at L3 before count visible). Spin is relaxed;
// a WORKGROUP-scope acquire fence gives compiler ordering WITHOUT buffer_inv,
// so per-XCD L2 keeps weights resident across barriers.
__device__ __forceinline__ void fence_acq_wg() {
  __builtin_amdgcn_fence(__ATOMIC_ACQUIRE, "workgroup");
}

// flat 16-block barrier (one decoder batch), own cache line
__device__ __forceinline__ void bar16(u32* base) {
  __syncthreads();
  if (threadIdx.x == 0) {
    u32* cnt = base; u32* gen = base + 1;
    u32 g = __hip_atomic_load(gen, __ATOMIC_RELAXED, __HIP_MEMORY_SCOPE_AGENT);
    u32 old = __hip_atomic_fetch_add(cnt, 1u, __ATOMIC_RELEASE, __HIP_MEMORY_SCOPE_AGENT);
    if (old == 15u) {
      __hip_atomic_store(cnt, 0u, __ATOMIC_RELAXED, __HIP_MEMORY_SCOPE_AGENT);
      __hip_atomic_fetch_add(gen, 1u, __ATOMIC_RELEASE, __HIP_MEMORY_SCOPE_AGENT);
    } else {
      while (__hip_atomic_load(gen, __ATOMIC_RELAXED, __HIP_MEMORY_SCOPE_AGENT) == g)
        __builtin_amdgcn_s_sleep(4);
    }
    fence_acq_wg();
  }
  __syncthreads();
}

// two-level tree barrier: 20 groups of 8 blocks, root over 20 leaders
__device__ __forceinline__ void bar_tree(u32* root, u32* grp) {
  __syncthreads();
  if (threadIdx.x == 0) {
    u32* gcnt = grp;  u32* ggen = grp + 1;
    u32 gg = __hip_atomic_load(ggen, __ATOMIC_RELAXED, __HIP_MEMORY_SCOPE_AGENT);
    u32 old = __hip_atomic_fetch_add(gcnt, 1u, __ATOMIC_RELEASE, __HIP_MEMORY_SCOPE_AGENT);
    if (old == 7u) {                          // last of group -> go to root
      u32* rcnt = root; u32* rgen = root + 1;
      u32 rg = __hip_atomic_load(rgen, __ATOMIC_RELAXED, __HIP_MEMORY_SCOPE_AGENT);
      u32 rold = __hip_atomic_fetch_add(rcnt, 1u, __ATOMIC_RELEASE, __HIP_MEMORY_SCOPE_AGENT);
      if (rold == 19u) {
        __hip_atomic_store(rcnt, 0u, __ATOMIC_RELAXED, __HIP_MEMORY_SCOPE_AGENT);
        __hip_atomic_fetch_add(rgen, 1u, __ATOMIC_RELEASE, __HIP_MEMORY_SCOPE_AGENT);
      } else {
        while (__hip_atomic_load(rgen, __ATOMIC_RELAXED, __HIP_MEMORY_SCOPE_AGENT) == rg)
          __builtin_amdgcn_s_sleep(4);
      }
      __hip_atomic_store(gcnt, 0u, __ATOMIC_RELAXED, __HIP_MEMORY_SCOPE_AGENT);
      __hip_atomic_fetch_add(ggen, 1u, __ATOMIC_RELEASE, __HIP_MEMORY_SCOPE_AGENT);
    } else {
      while (__hip_atomic_load(ggen, __ATOMIC_RELAXED, __HIP_MEMORY_SCOPE_AGENT) == gg)
        __builtin_amdgcn_s_sleep(4);
    }
    fence_acq_wg();
  }
  __syncthreads();
}

__device__ __forceinline__ u32 orderb(float f) {
  u32 u = __float_as_uint(f);
  return (u & 0x80000000u) ? ~u : (u | 0x80000000u);
}
__device__ __forceinline__ float unorderb(u32 u) {
  return __uint_as_float((u & 0x80000000u) ? (u & 0x7fffffffu) : ~u);
}
__device__ __forceinline__ u64 sx64(u64 v, int m) {
  u32 lo = __shfl_xor((u32)v, m, 64);
  u32 hi = __shfl_xor((u32)(v >> 32), m, 64);
  return (((u64)hi) << 32) | lo;
}
__device__ __forceinline__ double sxd(double v, int m) {
  u64 b = (u64)__double_as_longlong(v);
  u32 lo = __shfl_xor((u32)b, m, 64);
  u32 hi = __shfl_xor((u32)(b >> 32), m, 64);
  return __longlong_as_double((long long)((((u64)hi) << 32) | lo));
}

// ================= prep: weight packing + state init =================
__global__ void k_prep(const float* __restrict__ eWih, const float* __restrict__ eWhh,
                       const float* __restrict__ pW,   const float* __restrict__ emb,
                       const float* __restrict__ dWih, const float* __restrict__ dWhh,
                       const float* __restrict__ dbb,  const float* __restrict__ We,
                       const float* __restrict__ Wd,   const float* __restrict__ Wo,
                       float* __restrict__ ws)
{
  const size_t stride = (size_t)gridDim.x * blockDim.x;
  int* wsi = (int*)ws;
  for (size_t e = (size_t)blockIdx.x * blockDim.x + threadIdx.x; e < ETOT; e += stride) {
    if (e < E0) {                          // Wenc [kb][kk1104][jt8][g4]
      size_t kb = e / 35328, r = e % 35328;
      size_t kk = r >> 5, r2 = r & 31, jt = r2 >> 2, g = r2 & 3;
      size_t row = g * 1024 + kb * 8 + jt;
      ws[O_WENC + e] = (kk < 1024) ? eWhh[row * 1024 + kk] : eWih[row * 80 + (kk - 1024)];
    } else if (e < E1) { size_t t = e - E0; // Wproj [pb][kk1024][jt8][c4]
      size_t pb = t / 32768, r = t % 32768;
      size_t kk = r >> 5, r2 = r & 31, jt = r2 >> 2, c = r2 & 3;
      ws[O_WPROJ + t] = pW[(pb * 32 + jt * 4 + c) * 1024 + kk];
    } else if (e < E2) { size_t t = e - E1; // WeP [ub][kk512][jt8][c4]
      size_t ub = t / 16384, r = t % 16384;
      size_t kk = r >> 5, r2 = r & 31, jt = r2 >> 2, c = r2 & 3;
      ws[O_WE + t] = We[(ub * 32 + jt * 4 + c) * 512 + kk];
    } else if (e < E3) { size_t t = e - E2; // WdP [js][kk512][jt16][c4]
      size_t js = t / 32768, r = t % 32768;
      size_t kk = r >> 6, r2 = r & 63, jt = r2 >> 2, c = r2 & 3;
      ws[O_WD + t] = Wd[(js * 64 + jt * 4 + c) * 512 + kk];
    } else if (e < E4) { size_t t = e - E3; // WoT [kk512][56]
      size_t kk = t / 56, vv = t % 56;
      ws[O_WO + t] = (vv < 54) ? Wo[vv * 512 + kk] : 0.f;
    } else if (e < E5) { size_t t = e - E4; // dWP [ks][kk512][kl64][g4]
      size_t ks = t / 131072, r = t % 131072;
      size_t kk = r >> 8, r2 = r & 255, kl = r2 >> 2, g = r2 & 3;
      ws[O_DWP + t] = dWhh[(g * 512 + ks * 64 + kl) * 512 + kk];
    } else if (e < E6) { size_t t = e - E5; // Memb [tok][2048] = dWih@emb + db
      size_t tok = t / 2048, j = t % 2048;
      double s = 0.0;
      const float* wr = dWih + j * 256;
      const float* er = emb + tok * 256;
      for (int q = 0; q < 256; ++q) s += (double)wr[q] * (double)er[q];
      ws[O_MEMB + t] = (float)(s + (double)dbb[j]);
    } else if (e < E7)  { ws[O_HBUF + 16384 + (e - E6)] = 0.f; }
    else if (e < E8)  { ws[O_HDEC + (e - E7)] = 0.f; }
    else if (e < E9)  { ws[O_CDEC + (e - E8)] = 0.f; }
    else if (e < E10) { size_t t = e - E9; ws[O_CUM + t] = ((t & 3) == 0) ? 0.f : -1000000000.0f; }
    else if (e < E11) { wsi[O_SEQS + (e - E10)] = 0; }
    else if (e < E12) { wsi[O_LENS + (e - E11)] = 0; }
    else              { wsi[O_BAR + (e - E12)] = 0; }
  }
}

// ================= encoder + projection + joint-We precompute =================
// 160 blocks: [0,128) encoder (8 units x 4 gates x 16 batches, c in LDS),
// [128,144) projection (1 step behind), [144,160) u = We@p + bj (2 behind).
__global__ __launch_bounds__(256, 1) void k_enc(
    const float* __restrict__ xin, const float* __restrict__ encb,
    const float* __restrict__ projb, const float* __restrict__ bjv,
    float* __restrict__ ws)
{
  __shared__ float  s_hx[8832];   // [<=552 rows][16 b]
  __shared__ double s_redd[8192]; // rows 0..15 = h-part, 16..31 = x-part
  __shared__ float  s_bb[32];
  __shared__ float  s_c128[128];  // encoder c-state: [b16][jt8] at t = bf*8+jt
  const int tid = threadIdx.x, blk = blockIdx.x;
  const int kc = tid >> 5, bt = (tid >> 3) & 3, jt = tid & 7;
  u32* barR = (u32*)ws + O_BAR;
  u32* barG = (u32*)ws + O_BAR + 32 * (1 + (blk >> 3));
  float* hb = ws + O_HBUF;
  float* prn = ws + O_PRING;
  float* ua = ws + O_UALL;

  if (tid < 32) {
    if (blk < 128)      s_bb[tid] = encb[(tid >> 3) * 1024 + blk * 8 + (tid & 7)];
    else if (blk < 144) s_bb[tid] = projb[(blk - 128) * 32 + tid];
    else                s_bb[tid] = bjv[(blk - 144) * 32 + tid];
  }
  if (tid < 128) s_c128[tid] = 0.f;
  __syncthreads();

  for (int i = 0; i < 1026; ++i) {
    if (blk < 128 && i < 1024) {
      // ---- encoder LSTM step t=i: z = (x@Wih.T)_f32 + (h@Whh.T)_f32 + b ----
      const int par = (i + 1) & 1;
      double ah[16], ax[16];
      #pragma unroll
      for (int r = 0; r < 16; ++r) { ah[r] = 0.0; ax[r] = 0.0; }
      const float4* wb = (const float4*)(ws + O_WENC) + ((size_t)blk * 8832 + (size_t)kc * 552 + jt);
      // pass 0: kk 0..551 (all h)
      for (int e = tid; e < 8832; e += 256) s_hx[e] = AL(hb + par * 16384 + e);
      __syncthreads();
      {
        const float* hxp = s_hx + kc * 1104 + bt * 4;
        for (int q = 0; q < 69; ++q) {
          const float4 w4 = wb[(size_t)q * 8];
          const float4 h4 = *(const float4*)(hxp + q * 16);
          FMA16D(ah, w4, h4);
        }
      }
      __syncthreads();
      // pass 1: kk 552..1103 (h below 1024, x above)
      for (int e = tid; e < 8832; e += 256) {
        float v;
        if (e < 7552) v = AL(hb + par * 16384 + 8832 + e);
        else { const int f = (e - 7552) >> 4, bq = e & 15;
               v = xin[((size_t)bq * 1024 + i) * 80 + f]; }
        s_hx[e] = v;
      }
      __syncthreads();
      {
        const float4* wp = wb + 4416;
        const float* hxp = s_hx + kc * 1104 + bt * 4;
        int qs = 472 - kc * 69; qs = qs < 0 ? 0 : (qs > 69 ? 69 : qs);
        for (int q = 0; q < qs; ++q) {
          const float4 w4 = wp[(size_t)q * 8];
          const float4 h4 = *(const float4*)(hxp + q * 16);
          FMA16D(ah, w4, h4);
        }
        for (int q = qs; q < 69; ++q) {
          const float4 w4 = wp[(size_t)q * 8];
          const float4 h4 = *(const float4*)(hxp + q * 16);
          FMA16D(ax, w4, h4);
        }
      }
      __syncthreads();
      #pragma unroll
      for (int r = 0; r < 16; ++r) {
        s_redd[r * 256 + tid] = ah[r];
        s_redd[(16 + r) * 256 + tid] = ax[r];
      }
      __syncthreads();
      if (tid < 128) {           // epilogue: one (unit, batch) pair per thread
        const int jt2 = tid & 7, bf = tid >> 3;
        const int lane32 = (bf >> 2) * 8 + jt2, j = bf & 3;
        float z[4];
        #pragma unroll
        for (int g = 0; g < 4; ++g) {
          const int r = g * 4 + j;
          double sh = 0.0, sx = 0.0;
          #pragma unroll
          for (int k8 = 0; k8 < 8; ++k8) {
            sh += s_redd[r * 256 + k8 * 32 + lane32];
            sx += s_redd[(16 + r) * 256 + k8 * 32 + lane32];
          }
          z[g] = __fadd_rn(__fadd_rn((float)sx, (float)sh), s_bb[g * 8 + jt2]);
        }
        const float cold = s_c128[tid];
        const float cn = __fadd_rn(__fmul_rn(sig_np(z[1]), cold),
                                   __fmul_rn(sig_np(z[0]), tanh_np(z[2])));
        const float hn = __fmul_rn(sig_np(z[3]), tanh_np(cn));
        s_c128[tid] = cn;
        AS(hb + (i & 1) * 16384 + (blk * 8 + jt2) * 16 + bf, hn);
      }
    } else if (blk >= 128 && blk < 144 && i >= 1 && i <= 1024) {
      // ---- projection of h_{i-1}: h@proj_W.T + proj_b ----
      const int pb = blk - 128, par = (i + 1) & 1;
      double ah[16];
      #pragma unroll
      for (int r = 0; r < 16; ++r) ah[r] = 0.0;
      const float4* wb = (const float4*)(ws + O_WPROJ) + ((size_t)pb * 8192 + (size_t)kc * 512 + jt);
      for (int pass = 0; pass < 2; ++pass) {
        for (int e = tid; e < 8192; e += 256)
          s_hx[e] = AL(hb + par * 16384 + pass * 8192 + e);
        __syncthreads();
        const float4* wp = wb + (size_t)pass * 4096;
        const float* hxp = s_hx + kc * 1024 + bt * 4;
        for (int q = 0; q < 64; ++q) {
          const float4 w4 = wp[(size_t)q * 8];
          const float4 h4 = *(const float4*)(hxp + q * 16);
          FMA16D(ah, w4, h4);
        }
        __syncthreads();
      }
      #pragma unroll
      for (int r = 0; r < 16; ++r) s_redd[r * 256 + tid] = ah[r];
      __syncthreads();
      if (tid < 128) {
        const int jt2 = tid & 7, bf = tid >> 3;
        const int lane32 = (bf >> 2) * 8 + jt2, j = bf & 3;
        #pragma unroll
        for (int c = 0; c < 4; ++c) {
          const int r = c * 4 + j;
          double s0 = 0.0;
          #pragma unroll
          for (int k8 = 0; k8 < 8; ++k8) s0 += s_redd[r * 256 + k8 * 32 + lane32];
          AS(prn + (i & 1) * 8192 + (pb * 32 + jt2 * 4 + c) * 16 + bf,
             __fadd_rn((float)s0, s_bb[jt2 * 4 + c]));
        }
      }
    } else if (blk >= 144 && i >= 2) {
      // ---- u = p_{i-2}@We.T + bj ----
      const int ub = blk - 144, par = (i + 1) & 1, sv = i - 2;
      double ah[16];
      #pragma unroll
      for (int r = 0; r < 16; ++r) ah[r] = 0.0;
      const float4* wb = (const float4*)(ws + O_WE) + ((size_t)ub * 4096 + (size_t)kc * 512 + jt);
      for (int e = tid; e < 8192; e += 256) s_hx[e] = AL(prn + par * 8192 + e);
      __syncthreads();
      {
        const float* hxp = s_hx + kc * 1024 + bt * 4;
        for (int q = 0; q < 64; ++q) {
          const float4 w4 = wb[(size_t)q * 8];
          const float4 h4 = *(const float4*)(hxp + q * 16);
          FMA16D(ah, w4, h4);
        }
      }
      __syncthreads();
      #pragma unroll
      for (int r = 0; r < 16; ++r) s_redd[r * 256 + tid] = ah[r];
      __syncthreads();
      if (tid < 128) {
        const int jt2 = tid & 7, bf = tid >> 3;
        const int lane32 = (bf >> 2) * 8 + jt2, j = bf & 3;
        #pragma unroll
        for (int c = 0; c < 4; ++c) {
          const int r = c * 4 + j;
          double s0 = 0.0;
          #pragma unroll
          for (int k8 = 0; k8 < 8; ++k8) s0 += s_redd[r * 256 + k8 * 32 + lane32];
          ua[((size_t)bf * 1024 + sv) * 512 + ub * 32 + jt2 * 4 + c] =
              __fadd_rn((float)s0, s_bb[jt2 * 4 + c]);   // plain store, read next kernel
        }
      }
    }
    bar_tree(barR, barG);
  }
}

// ================= beam-search decoder =================
// Per-batch independent: 16 blocks/batch with their own 16-block barrier.
// Block map: g=blk&7 (XCD slot = dWhh slice), q=blk>>3, par=q&1, b=q>>1 ->
// each XCD holds one 512KB dWhh slice + one 128KB Wd slice -> L2-resident.
// Phase A (par==0, 8 blocks): v = tanh(u + Wd h). Phase B (all 16): redundant
// logits/softmax/top-k (bit-identical) + LSTM update of own 32 units.
__global__ __launch_bounds__(256, 1) void k_dec(
    const int* __restrict__ linp, const float* __restrict__ bo,
    int* __restrict__ outp, float* __restrict__ ws)
{
  __shared__ float  s_h[2048], s_v[2048], s_c[128];
  __shared__ double s_redd[4096];
  __shared__ float  s_cand[216];
  __shared__ int s_parent[4], s_tok[4], s_plen[4], s_emit[4];
  __shared__ float s_val[4];
  const int tid = threadIdx.x, blk = blockIdx.x;
  const int g = blk & 7, q = blk >> 3, par = q & 1, b = q >> 1;
  const int L = linp[b];
  u32* barB = (u32*)ws + O_BAR + 32 * (21 + b);
  float* hd = ws + O_HDEC;
  float* cd = ws + O_CDEC;
  float* vb = ws + O_VBUF;
  float* cum = ws + O_CUM;
  int* seqs = (int*)ws + O_SEQS;
  int* lensr = (int*)ws + O_LENS;

  for (int s = 0; s < L; ++s) {
    const int cur = s & 1, nxt = cur ^ 1;
    for (int e = tid; e < 2048; e += 256) s_h[e] = AL(hd + cur * 32768 + b * 2048 + e);
    if (tid < 128)
      s_c[tid] = AL(cd + cur * 32768 + b * 2048 + (tid >> 5) * 512 + g * 64 + par * 32 + (tid & 31));
    __syncthreads();
    if (par == 0) {
      // phase A: v-slice js=g: t = u + (h@Wd.T); v = tanh(t)
      const int js = g, kcA = tid >> 4, jt4 = tid & 15;
      double a[16];
      #pragma unroll
      for (int r = 0; r < 16; ++r) a[r] = 0.0;
      const float4* wp = (const float4*)(ws + O_WD) + ((size_t)js * 8192 + (size_t)kcA * 512 + jt4);
      for (int q2 = 0; q2 < 32; ++q2) {
        const float4 w4 = wp[(size_t)q2 * 16];
        const int kk = kcA * 32 + q2;
        const double wx = w4.x, wy = w4.y, wz = w4.z, ww = w4.w;
        #pragma unroll
        for (int w = 0; w < 4; ++w) {
          const double hv = (double)s_h[w * 512 + kk];
          a[w * 4 + 0] += wx * hv; a[w * 4 + 1] += wy * hv;
          a[w * 4 + 2] += wz * hv; a[w * 4 + 3] += ww * hv;
        }
      }
      #pragma unroll
      for (int r = 0; r < 16; ++r) s_redd[r * 256 + tid] = a[r];
      __syncthreads();
      {                          // epilogue: all 256 threads, 1 tanh each
        const int r = tid >> 4, t16 = tid & 15;
        double S = 0.0;
        #pragma unroll
        for (int k16 = 0; k16 < 16; ++k16) S += s_redd[r * 256 + k16 * 16 + t16];
        const int w = r >> 2, c = r & 3;
        const float uv = ws[O_UALL + ((size_t)b * 1024 + s) * 512 + js * 64 + t16 * 4 + c];
        AS(vb + b * 2048 + w * 512 + js * 64 + t16 * 4 + c,
           tanh_np(__fadd_rn(uv, (float)S)));
      }
    }
    bar16(barB);
    {
      for (int e = tid; e < 2048; e += 256) s_v[e] = AL(vb + b * 2048 + e);
      __syncthreads();
      if (tid < 216) {            // logits = v@Wo.T + bo (4-way ILP)
        const int w = tid / 54, vv = tid - w * 54;
        const float* wo = ws + O_WO + vv;
        const float* vr = s_v + w * 512;
        double a0 = 0.0, a1 = 0.0, a2 = 0.0, a3 = 0.0;
        for (int kk = 0; kk < 512; kk += 4) {
          a0 += (double)vr[kk]     * (double)wo[(size_t)kk * 56];
          a1 += (double)vr[kk + 1] * (double)wo[(size_t)(kk + 1) * 56];
          a2 += (double)vr[kk + 2] * (double)wo[(size_t)(kk + 2) * 56];
          a3 += (double)vr[kk + 3] * (double)wo[(size_t)(kk + 3) * 56];
        }
        s_cand[tid] = __fadd_rn((float)((a0 + a1) + (a2 + a3)), bo[vv]);
      }
      __syncthreads();
      {                           // log_softmax + cum -> candidates
        const int w = tid >> 6, lane = tid & 63;
        const float val = (lane < 54) ? s_cand[w * 54 + lane] : -3.0e38f;
        float m = val;
        #pragma unroll
        for (int off = 32; off > 0; off >>= 1) m = fmaxf(m, __shfl_xor(m, off, 64));
        const float sh = __fsub_rn(val, m);
        const float exf = (lane < 54) ? (float)exp((double)sh) : 0.f;
        double sum = (double)exf;
        #pragma unroll
        for (int off = 32; off > 0; off >>= 1) sum += sxd(sum, off);
        const float Sf = (float)sum;
        const float lg = (float)log((double)Sf);
        const float cw = AL(cum + cur * 64 + b * 4 + w);
        if (lane < 54) s_cand[w * 54 + lane] = __fadd_rn(cw, __fsub_rn(sh, lg));
      }
      __syncthreads();
      if (tid < 64) {             // top-4 of 216, lax.top_k tie-break (lower idx)
        u64 k4[4];
        #pragma unroll
        for (int p = 0; p < 4; ++p) {
          const int idx = tid + p * 64;
          k4[p] = (idx < 216) ? ((((u64)orderb(s_cand[idx])) << 32) | (u32)(~(u32)idx)) : 0ull;
        }
        #pragma unroll
        for (int sel = 0; sel < 4; ++sel) {
          u64 best = k4[0];
          if (k4[1] > best) best = k4[1];
          if (k4[2] > best) best = k4[2];
          if (k4[3] > best) best = k4[3];
          #pragma unroll
          for (int off = 32; off > 0; off >>= 1) { u64 o = sx64(best, off); if (o > best) best = o; }
          const u32 wid = ~((u32)best);
          if (tid == 0) {
            s_parent[sel] = (int)(wid / 54u);
            s_tok[sel] = (int)(wid - (wid / 54u) * 54u);
            s_val[sel] = unorderb((u32)(best >> 32));
          }
          #pragma unroll
          for (int p = 0; p < 4; ++p) if ((u32)(tid + p * 64) == wid) k4[p] = 0ull;
        }
        if (tid == 0) {
          #pragma unroll
          for (int w = 0; w < 4; ++w) {
            const int pl = AL(lensr + cur * 64 + b * 4 + s_parent[w]);
            s_plen[w] = pl;
            s_emit[w] = (s_tok[w] != 0 && pl < 54) ? 1 : 0;
          }
        }
      }
      __syncthreads();
      if (g == 0 && par == 0) {   // single writer of seqs/lens/cum rings
        if (tid < 4) {
          AS(cum + nxt * 64 + b * 4 + tid, s_val[tid]);
          AS(lensr + nxt * 64 + b * 4 + tid, s_plen[tid] + s_emit[tid]);
        }
        for (int e = tid; e < 220; e += 256) {
          const int w = e / 55, m = e - w * 55;
          int v = AL(seqs + cur * 3584 + (b * 4 + s_parent[w]) * 56 + m);
          if (s_emit[w] && m == s_plen[w]) v = s_tok[w];
          AS(seqs + nxt * 3584 + (b * 4 + w) * 56 + m, v);
        }
      }
      {                           // decoder LSTM gates for this block's 32 units
        const int kc2 = tid >> 5, ul = tid & 31;
        double a[16];
        #pragma unroll
        for (int r = 0; r < 16; ++r) a[r] = 0.0;
        const float4* wp = (const float4*)(ws + O_DWP) +
            (size_t)g * 32768 + (size_t)kc2 * 4096 + par * 32 + ul;
        const int p0 = s_parent[0] * 512, p1 = s_parent[1] * 512,
                  p2 = s_parent[2] * 512, p3 = s_parent[3] * 512;
        for (int q2 = 0; q2 < 64; ++q2) {
          const float4 w4 = wp[(size_t)q2 * 64];
          const int kk = kc2 * 64 + q2;
          const double wx = w4.x, wy = w4.y, wz = w4.z, ww = w4.w;
          const double h0 = s_h[p0 + kk], h1 = s_h[p1 + kk],
                       h2 = s_h[p2 + kk], h3 = s_h[p3 + kk];
          a[0] += wx * h0;  a[1] += wy * h0;  a[2] += wz * h0;  a[3] += ww * h0;
          a[4] += wx * h1;  a[5] += wy * h1;  a[6] += wz * h1;  a[7] += ww * h1;
          a[8] += wx * h2;  a[9] += wy * h2;  a[10] += wz * h2; a[11] += ww * h2;
          a[12] += wx * h3; a[13] += wy * h3; a[14] += wz * h3; a[15] += ww * h3;
        }
        #pragma unroll
        for (int r = 0; r < 16; ++r) s_redd[r * 256 + tid] = a[r];
        __syncthreads();
        if (tid < 128) {          // epilogue: (w, unit) per thread
          const int w = tid >> 5, u = tid & 31;
          const int k = g * 64 + par * 32 + u;
          double z0 = 0.0, z1 = 0.0, z2 = 0.0, z3 = 0.0;
          #pragma unroll
          for (int kcq = 0; kcq < 8; ++kcq) {
            const int base = kcq * 32 + u;
            z0 += s_redd[(w * 4 + 0) * 256 + base];
            z1 += s_redd[(w * 4 + 1) * 256 + base];
            z2 += s_redd[(w * 4 + 2) * 256 + base];
            z3 += s_redd[(w * 4 + 3) * 256 + base];
          }
          const float* mb = ws + O_MEMB + (size_t)s_tok[w] * 2048;
          const float zi = __fadd_rn(mb[k], (float)z0);
          const float zf = __fadd_rn(mb[512 + k], (float)z1);
          const float zg = __fadd_rn(mb[1024 + k], (float)z2);
          const float zo = __fadd_rn(mb[1536 + k], (float)z3);
          const float cold = s_c[s_parent[w] * 32 + u];
          float cn = __fadd_rn(__fmul_rn(sig_np(zf), cold),
                               __fmul_rn(sig_np(zi), tanh_np(zg)));
          float hn = __fmul_rn(sig_np(zo), tanh_np(cn));
          if (!s_emit[w]) { hn = s_h[s_parent[w] * 512 + k]; cn = cold; }
          AS(hd + nxt * 32768 + b * 2048 + w * 512 + k, hn);
          AS(cd + nxt * 32768 + b * 2048 + w * 512 + k, cn);
        }
      }
    }
    bar16(barB);
  }
  if (g == 0 && par == 0) {       // emit outputs: total (64x55) then best (16x55)
    const int fc = L & 1;
    for (int e = tid; e < 220; e += 256) {
      const int w = e / 55, m = e - w * 55;
      const int ln = AL(lensr + fc * 64 + b * 4 + w);
      int v = AL(seqs + fc * 3584 + (b * 4 + w) * 56 + m);
      if (m == ln) v = 53;
      outp[(b * 4 + w) * 55 + m] = v;
      if (w == 0) outp[3520 + b * 55 + m] = v;
    }
  }
}

extern "C" void kernel_launch(void* const* d_in, const int* in_sizes, int n_in,
                              void* d_out, int out_size, void* d_ws, size_t ws_size,
                              hipStream_t stream) {
  (void)in_sizes; (void)n_in; (void)out_size; (void)ws_size;
  const float* xin  = (const float*)d_in[0];
  const int*   lin  = (const int*)d_in[1];
  const float* eWih = (const float*)d_in[3];
  const float* eWhh = (const float*)d_in[4];
  const float* eb   = (const float*)d_in[5];
  const float* pW   = (const float*)d_in[6];
  const float* pb   = (const float*)d_in[7];
  const float* emb  = (const float*)d_in[8];
  const float* dWih = (const float*)d_in[9];
  const float* dWhh = (const float*)d_in[10];
  const float* db   = (const float*)d_in[11];
  const float* We   = (const float*)d_in[12];
  const float* Wd   = (const float*)d_in[13];
  const float* bj   = (const float*)d_in[14];
  const float* Wo   = (const float*)d_in[15];
  const float* bo   = (const float*)d_in[16];
  float* ws = (float*)d_ws;
  int* outp = (int*)d_out;

  hipLaunchKernelGGL(k_prep, dim3(8192), dim3(256), 0, stream,
                     eWih, eWhh, pW, emb, dWih, dWhh, db, We, Wd, Wo, ws);
  hipLaunchKernelGGL(k_enc, dim3(160), dim3(256), 0, stream, xin, eb, pb, bj, ws);
  hipLaunchKernelGGL(k_dec, dim3(256), dim3(256), 0, stream, lin, bo, outp, ws);
}